// Round 1
// baseline (213.689 us; speedup 1.0000x reference)
//
#include <hip/hip_runtime.h>
#include <math.h>

// Problem constants (B=16, T=2, H=384, W=640)
#define NB   16
#define HW_  245760          // H*W
#define THW_ 491520          // 2*H*W
#define CAP  2048            // per-batch final candidate capacity (~1440-1650 used)
#define BIGF 1e30f
#define DELTAF 0.03f
#define H1SLICES 8           // global L1-histogram slices (contention relief)
#define NSEG 30              // K1 blocks per batch (8192 px each)
#define KSEGCAP 16384u       // worst-case masked keys per segment (2 frames * 8192 px)
#define TSEGCAP 8192u        // worst-case m12 tuples per segment

// ---- workspace layout (bytes) ----
#define SUMS_OFF   0u                                   // double[16*5]
#define HIST1_OFF  1024u                                // uint[16*8*4096] sliced
#define HIST2_OFF  (HIST1_OFF + NB*H1SLICES*4096u*4u)   // uint[16*4*4096]
#define CNT_OFF    (HIST2_OFF + NB*4u*4096u*4u)         // uint[16*64] (256B padded per batch)
#define DONE_OFF   (CNT_OFF + NB*256u)                  // uint[1] k6 completion counter
#define ZERO_BYTES (DONE_OFF + 64u)
#define PAR_OFF    ((ZERO_BYTES + 255u) & ~255u)
#define S_OFF      (PAR_OFF + 0u)      // float[16]
#define T_OFF      (PAR_OFF + 64u)     // float[16]
#define RR_OFF     (PAR_OFF + 128u)    // float[16]
#define NN_OFF     (PAR_OFF + 320u)    // int[16]
#define BIN_OFF    (PAR_OFF + 384u)    // int[16*4]
#define RK_OFF     (PAR_OFF + 640u)    // uint[16*4]
#define FR_OFF     (PAR_OFF + 896u)    // float[16*2]
#define LD_OFF     (PAR_OFF + 1024u)   // float[16]
#define LA_OFF     (PAR_OFF + 1088u)   // float[16]
#define THUB_OFF   (PAR_OFF + 1152u)   // float[16] conservative th upper bound
#define BUFD_OFF   (PAR_OFF + 2048u)   // float[16*CAP] |dpred-dgt|
#define BUFA_OFF   (BUFD_OFF + NB*CAP*4u)   // float[16*CAP] |dpred-prev|
#define BUFG_OFF   (BUFA_OFF + NB*CAP*4u)   // float[16*CAP] |dgt|
// ---- new: compact intermediates spilled by K1 (worst-case sized, no overflow) ----
#define KCNT_OFF   (BUFG_OFF + NB*CAP*4u)             // uint[16*30] per-segment key counts
#define TCNT_OFF   (KCNT_OFF + 2048u)                 // uint[16*30] per-segment tuple counts
#define KEYS_OFF   (TCNT_OFF + 2048u)                 // uint[16*30*16384]  (31.5 MB)
#define TUPD_OFF   (KEYS_OFF + NB*NSEG*KSEGCAP*4u)    // float[16*30*8192] dp_raw (15.7 MB)
#define TUPG_OFF   (TUPD_OFF + NB*NSEG*TSEGCAP*4u)    // float[16*30*8192] dg     (15.7 MB)
#define TUPP_OFF   (TUPG_OFF + NB*NSEG*TSEGCAP*4u)    // float[16*30*8192] prev   (15.7 MB)
// total ws use ≈ 82 MB << 256 MiB workspace

#define WS_SUMS(ws) ((double*)((ws) + SUMS_OFF))
#define WS_H1(ws)   ((unsigned*)((ws) + HIST1_OFF))
#define WS_H2(ws)   ((unsigned*)((ws) + HIST2_OFF))
#define WS_CNT(ws)  ((unsigned*)((ws) + CNT_OFF))      // index b*64
#define WS_DONE(ws) ((unsigned*)((ws) + DONE_OFF))
#define WS_S(ws)    ((float*)((ws) + S_OFF))
#define WS_T(ws)    ((float*)((ws) + T_OFF))
#define WS_RR(ws)   ((float*)((ws) + RR_OFF))
#define WS_NN(ws)   ((int*)((ws) + NN_OFF))
#define WS_BIN(ws)  ((int*)((ws) + BIN_OFF))
#define WS_RK(ws)   ((unsigned*)((ws) + RK_OFF))
#define WS_FR(ws)   ((float*)((ws) + FR_OFF))
#define WS_LD(ws)   ((float*)((ws) + LD_OFF))
#define WS_LA(ws)   ((float*)((ws) + LA_OFF))
#define WS_THUB(ws) ((float*)((ws) + THUB_OFF))
#define WS_BUFD(ws) ((float*)((ws) + BUFD_OFF))
#define WS_BUFA(ws) ((float*)((ws) + BUFA_OFF))
#define WS_BUFG(ws) ((float*)((ws) + BUFG_OFF))
#define WS_KCNT(ws) ((unsigned*)((ws) + KCNT_OFF))
#define WS_TCNT(ws) ((unsigned*)((ws) + TCNT_OFF))
#define WS_KEYS(ws) ((unsigned*)((ws) + KEYS_OFF))
#define WS_TUPD(ws) ((float*)((ws) + TUPD_OFF))
#define WS_TUPG(ws) ((float*)((ws) + TUPG_OFF))
#define WS_TUPP(ws) ((float*)((ws) + TUPP_OFF))

// order-preserving float<->uint key
__device__ __forceinline__ unsigned fkey(float x) {
    unsigned u = __float_as_uint(x);
    return (u & 0x80000000u) ? ~u : (u | 0x80000000u);
}
__device__ __forceinline__ float keyf(unsigned k) {
    unsigned u = (k & 0x80000000u) ? (k & 0x7fffffffu) : ~k;
    return __uint_as_float(u);
}

// Block-cooperative rank locate in a 4096-bin histogram (256 threads).
// Scan rewritten: wave-level __shfl_up + 4 wave totals (2 barriers instead of 16).
__device__ void locate_ranks(const unsigned* __restrict__ hist, unsigned* part,
                             const int* ranks, int nr, int* outBin, unsigned* outOff) {
    int tid = threadIdx.x;
    int lane = tid & 63, wid = tid >> 6;
    int base = tid * 16;
    unsigned hloc[16];
    unsigned csum = 0;
#pragma unroll
    for (int j = 0; j < 16; j++) { hloc[j] = hist[base + j]; csum += hloc[j]; }
    unsigned incl = csum;
#pragma unroll
    for (int d = 1; d < 64; d <<= 1) {
        unsigned t = __shfl_up(incl, d);
        if (lane >= d) incl += t;
    }
    if (lane == 63) part[wid] = incl;
    __syncthreads();
    unsigned wadd = 0;
    for (int w = 0; w < wid; w++) wadd += part[w];
    incl += wadd;
    unsigned excl = incl - csum;
    for (int q = 0; q < nr; q++) {
        int r = ranks[q];
        if (r >= (int)excl && r < (int)incl) {
            unsigned cum = excl;
#pragma unroll
            for (int j = 0; j < 16; j++) {
                unsigned h = hloc[j];
                if ((unsigned)r < cum + h) { outBin[q] = base + j; outOff[q] = (unsigned)r - cum; break; }
                cum += h;
            }
        }
    }
    __syncthreads();
}

// K1 (fused): single pass over all inputs. Per-batch regression sums (f64),
// L1 histogram of masked gt, raw dp=p1-p0 -> out (t cancels: dpred = s*(p1-p0)),
// ballot-compacted spill of masked gt keys + m12 tuples (dp_raw, dg, prev) into
// per-segment worst-case-sized regions (no atom>global counter contention,
// deterministic capacity). grid (30,16), block 512: 8192 px/block.
__global__ __launch_bounds__(512) void k1_fused(const float* __restrict__ pred,
                                                const float* __restrict__ gt,
                                                const float* __restrict__ mask,
                                                const float* __restrict__ prev,
                                                float* __restrict__ out,
                                                unsigned char* __restrict__ ws) {
    __shared__ unsigned hist[8192];
    __shared__ double red[8][5];
    __shared__ unsigned segCnt[2];   // [0]=keys, [1]=tuples
    int tid = threadIdx.x;
    int b = blockIdx.y, x = blockIdx.x;
    int lane = tid & 63, wid = tid >> 6;
    unsigned half = (tid >> 5) & 1u;
    for (int i = tid; i < 8192; i += 512) hist[i] = 0;
    if (tid < 2) segCnt[tid] = 0;
    __syncthreads();

    size_t hw0 = (size_t)x * 8192;
    const float* p0p = pred + (size_t)b * THW_ + hw0;
    const float* g0p = gt   + (size_t)b * THW_ + hw0;
    const float* m0p = mask + (size_t)b * THW_ + hw0;
    const float* pvp = prev + (size_t)b * HW_  + hw0;
    float* op = out + 4 + (size_t)b * HW_ + hw0;
    int segid = b * NSEG + x;
    unsigned* keySeg = WS_KEYS(ws) + (size_t)segid * KSEGCAP;
    float* tupD = WS_TUPD(ws) + (size_t)segid * TSEGCAP;
    float* tupG = WS_TUPG(ws) + (size_t)segid * TSEGCAP;
    float* tupP = WS_TUPP(ws) + (size_t)segid * TSEGCAP;
    unsigned long long premask = (1ull << lane) - 1ull;

    double a00 = 0, a01 = 0, a11 = 0, sb0 = 0, sb1 = 0;
    size_t off0 = (size_t)tid * 4;
    float4 cP0 = *(const float4*)(p0p + off0);
    float4 cP1 = *(const float4*)(p0p + HW_ + off0);
    float4 cG0 = *(const float4*)(g0p + off0);
    float4 cG1 = *(const float4*)(g0p + HW_ + off0);
    float4 cM0 = *(const float4*)(m0p + off0);
    float4 cM1 = *(const float4*)(m0p + HW_ + off0);
    float4 cPV = *(const float4*)(pvp + off0);
#pragma unroll
    for (int r = 0; r < 4; r++) {
        float4 nP0, nP1, nG0, nG1, nM0, nM1, nPV;
        if (r < 3) {
            size_t o2 = (size_t)(r + 1) * 2048 + (size_t)tid * 4;
            nP0 = *(const float4*)(p0p + o2);
            nP1 = *(const float4*)(p0p + HW_ + o2);
            nG0 = *(const float4*)(g0p + o2);
            nG1 = *(const float4*)(g0p + HW_ + o2);
            nM0 = *(const float4*)(m0p + o2);
            nM1 = *(const float4*)(m0p + HW_ + o2);
            nPV = *(const float4*)(pvp + o2);
        }
        float p0a[4] = {cP0.x, cP0.y, cP0.z, cP0.w};
        float p1a[4] = {cP1.x, cP1.y, cP1.z, cP1.w};
        float g0a[4] = {cG0.x, cG0.y, cG0.z, cG0.w};
        float g1a[4] = {cG1.x, cG1.y, cG1.z, cG1.w};
        float m0a[4] = {cM0.x, cM0.y, cM0.z, cM0.w};
        float m1a[4] = {cM1.x, cM1.y, cM1.z, cM1.w};
        float pva[4] = {cPV.x, cPV.y, cPV.z, cPV.w};
        bool mm0[4], mm1[4], m12[4];
        unsigned k0[4], k1v[4];
        float dpv[4];
#pragma unroll
        for (int c = 0; c < 4; c++) {
            mm0[c] = m0a[c] > 0.5f;
            mm1[c] = m1a[c] > 0.5f;
            m12[c] = mm0[c] && mm1[c];
            dpv[c] = p1a[c] - p0a[c];
            k0[c] = fkey(g0a[c]);
            k1v[c] = fkey(g1a[c]);
            if (mm0[c]) {
                float pv = p0a[c], gv = g0a[c];
                a00 += (double)(pv * pv); a01 += (double)pv; a11 += 1.0;
                sb0 += (double)(pv * gv); sb1 += (double)gv;
                atomicAdd(&hist[((k0[c] >> 20) << 1) | half], 1u);
            }
            if (mm1[c]) {
                float pv = p1a[c], gv = g1a[c];
                a00 += (double)(pv * pv); a01 += (double)pv; a11 += 1.0;
                sb0 += (double)(pv * gv); sb1 += (double)gv;
                atomicAdd(&hist[((k1v[c] >> 20) << 1) | half], 1u);
            }
        }
        // raw dp -> out (scaled by s in k2)
        *(float4*)(op + (size_t)r * 2048 + (size_t)tid * 4) =
            make_float4(dpv[0], dpv[1], dpv[2], dpv[3]);
        // ballot-compacted key append (8 groups; wave-uniform branches)
#pragma unroll
        for (int c = 0; c < 4; c++) {
            unsigned long long bal = __ballot(mm0[c]);
            if (bal) {
                unsigned cnt = (unsigned)__popcll(bal);
                unsigned pre = (unsigned)__popcll(bal & premask);
                unsigned base = 0;
                if (lane == 0) base = atomicAdd(&segCnt[0], cnt);
                base = __shfl(base, 0);
                if (mm0[c]) keySeg[base + pre] = k0[c];
            }
            bal = __ballot(mm1[c]);
            if (bal) {
                unsigned cnt = (unsigned)__popcll(bal);
                unsigned pre = (unsigned)__popcll(bal & premask);
                unsigned base = 0;
                if (lane == 0) base = atomicAdd(&segCnt[0], cnt);
                base = __shfl(base, 0);
                if (mm1[c]) keySeg[base + pre] = k1v[c];
            }
        }
        // ballot-compacted m12 tuple append
#pragma unroll
        for (int c = 0; c < 4; c++) {
            unsigned long long bal = __ballot(m12[c]);
            if (bal) {
                unsigned cnt = (unsigned)__popcll(bal);
                unsigned pre = (unsigned)__popcll(bal & premask);
                unsigned base = 0;
                if (lane == 0) base = atomicAdd(&segCnt[1], cnt);
                base = __shfl(base, 0);
                if (m12[c]) {
                    unsigned p = base + pre;
                    tupD[p] = dpv[c];
                    tupG[p] = g1a[c] - g0a[c];
                    tupP[p] = pva[c];
                }
            }
        }
        if (r < 3) { cP0 = nP0; cP1 = nP1; cG0 = nG0; cG1 = nG1; cM0 = nM0; cM1 = nM1; cPV = nPV; }
    }
    __syncthreads();
    if (tid == 0) { WS_KCNT(ws)[segid] = segCnt[0]; WS_TCNT(ws)[segid] = segCnt[1]; }
    // flush nonzero bins to this block's slice, rotated start spreads lines
    unsigned* gh = WS_H1(ws) + ((size_t)b * H1SLICES + (unsigned)(x & (H1SLICES - 1))) * 4096u;
    unsigned rot = ((unsigned)x * 331u) & 4095u;
    for (int i = tid; i < 4096; i += 512) {
        int bin = (int)(((unsigned)i + rot) & 4095u);
        unsigned v = hist[bin * 2] + hist[bin * 2 + 1];
        if (v) atomicAdd(&gh[bin], v);
    }
    double acc[5] = {a00, a01, a11, sb0, sb1};
#pragma unroll
    for (int j = 0; j < 5; j++) {
        double v = acc[j];
        for (int o = 32; o > 0; o >>= 1) v += __shfl_down(v, o);
        if (lane == 0) red[wid][j] = v;
    }
    __syncthreads();
    if (tid == 0) {
        double* gs = WS_SUMS(ws) + b * 5;
#pragma unroll
        for (int j = 0; j < 5; j++) {
            double tot = 0.0;
#pragma unroll
            for (int w = 0; w < 8; w++) tot += red[w][j];
            atomicAdd(&gs[j], tot);
        }
    }
}

// K2: grid (60,16) x 256. ALL blocks: recompute s from sums (5 loads, identical
// expression -> bit-identical to WS_S) and scale their out slice in place.
// Block x==0 additionally: s,t,NN; sum H1 slices; quantile ranks; L1 bins; th_ub.
__global__ __launch_bounds__(256) void k2_rank_scale(float* __restrict__ out,
                                                     unsigned char* __restrict__ ws) {
    __shared__ unsigned hsum[4096];
    __shared__ unsigned part[256];
    int b = blockIdx.y, x = blockIdx.x, tid = threadIdx.x;
    const double* gs = WS_SUMS(ws) + b * 5;
    double a00 = gs[0], a01 = gs[1], a11 = gs[2], b0 = gs[3], b1 = gs[4];
    double det = a00 * a11 - a01 * a01;
    float s_loc = 0.0f;
    if (det != 0.0) s_loc = (float)((a11 * b0 - a01 * b1) / (det + 1e-6));
    // scale out slice: dpred = s*(p1-p0); t cancels
    float* op = out + 4 + (size_t)b * HW_ + (size_t)x * 4096;
#pragma unroll
    for (int r = 0; r < 4; r++) {
        size_t off = (size_t)r * 1024 + (size_t)tid * 4;
        float4 v = *(const float4*)(op + off);
        v.x *= s_loc; v.y *= s_loc; v.z *= s_loc; v.w *= s_loc;
        *(float4*)(op + off) = v;
    }
    if (x != 0) return;

    int n = (int)(a11 + 0.5);
    if (tid == 0) {
        double x0 = 0.0, x1 = 0.0;
        if (det != 0.0) {
            x0 = (a11 * b0 - a01 * b1) / (det + 1e-6);
            x1 = (-a01 * b0 + a00 * b1) / (det + 1e-6);
        }
        WS_S(ws)[b] = (float)x0;
        WS_T(ws)[b] = (float)x1;
        WS_NN(ws)[b] = n;
    }
    // reduce slices: thread t owns bins [t*16, t*16+16)
    {
        const unsigned* h1 = WS_H1(ws) + (size_t)b * H1SLICES * 4096u;
        int base = tid * 16;
        unsigned acc[16];
#pragma unroll
        for (int j = 0; j < 16; j++) acc[j] = 0;
        for (int s = 0; s < H1SLICES; s++) {
            const unsigned* hs = h1 + (size_t)s * 4096u + base;
#pragma unroll
            for (int j = 0; j < 16; j++) acc[j] += hs[j];
        }
#pragma unroll
        for (int j = 0; j < 16; j++) hsum[base + j] = acc[j];
    }
    __syncthreads();
    float nm1 = (float)((n - 1 > 0) ? (n - 1) : 0);
    float p05 = 0.05f * nm1, p95 = 0.95f * nm1;   // f32 to match JAX weak-type promotion
    int ranks[4] = {(int)floorf(p05), (int)ceilf(p05), (int)floorf(p95), (int)ceilf(p95)};
    float f05 = p05 - floorf(p05), f95 = p95 - floorf(p95);
    if (tid == 0) {
        WS_FR(ws)[b * 2 + 0] = f05;
        WS_FR(ws)[b * 2 + 1] = f95;
    }
    if (n > 0) {
        locate_ranks(hsum, part, ranks, 4, WS_BIN(ws) + b * 4, WS_RK(ws) + b * 4);
        if (tid == 0) {
            const int* bp = WS_BIN(ws) + b * 4;
            float lb0 = keyf(((unsigned)bp[0]) << 20), ub0 = keyf((((unsigned)bp[0]) << 20) | 0xFFFFFu);
            float lb1 = keyf(((unsigned)bp[1]) << 20), ub1 = keyf((((unsigned)bp[1]) << 20) | 0xFFFFFu);
            float lb2 = keyf(((unsigned)bp[2]) << 20), ub2 = keyf((((unsigned)bp[2]) << 20) | 0xFFFFFu);
            float lb3 = keyf(((unsigned)bp[3]) << 20), ub3 = keyf((((unsigned)bp[3]) << 20) | 0xFFFFFu);
            float qlo_lb = (1.0f - f05) * lb0 + f05 * lb1;
            float qlo_ub = (1.0f - f05) * ub0 + f05 * ub1;
            float qhi_lb = (1.0f - f95) * lb2 + f95 * lb3;
            float qhi_ub = (1.0f - f95) * ub2 + f95 * ub3;
            float rr_ub = fmaxf(qhi_ub - qlo_lb, 1e-6f);
            if (qhi_lb - qlo_ub <= 0.0f) rr_ub = fmaxf(rr_ub, 1.0f);
            WS_THUB(ws)[b] = 0.01f * rr_ub * 1.0001f;   // tiny safety margin
        }
    } else if (tid == 0) {
        WS_THUB(ws)[b] = 0.0f;   // no masked pixels -> nothing static
        int* bp = WS_BIN(ws) + b * 4;
        bp[0] = bp[1] = bp[2] = bp[3] = -1;
    }
}

// K3: compact pass only (~27.5 MB, was 126 MB in the old k5). Per segment:
// (B) L2-histogram population for the 4 selected L1 bins from the spilled key
// list; (C) conservative thub filter of the spilled m12 tuples -> final CAP
// buffers (per-hit global atomic: ~1600/batch, negligible contention).
// grid (30,16), block 256.
__global__ __launch_bounds__(256) void k3_h2_filter(unsigned char* __restrict__ ws) {
    int b = blockIdx.y, x = blockIdx.x, tid = threadIdx.x;
    float s = WS_S(ws)[b], thub = WS_THUB(ws)[b];
    const int* bp = WS_BIN(ws) + b * 4;
    int bn0 = bp[0], bn1 = bp[1], bn2 = bp[2], bn3 = bp[3];
    int segid = b * NSEG + x;
    unsigned nk = WS_KCNT(ws)[segid];
    const unsigned* keys = WS_KEYS(ws) + (size_t)segid * KSEGCAP;
    unsigned* h2 = WS_H2(ws);
    for (unsigned i = tid; i < nk; i += 256) {
        unsigned key = keys[i];
        int top = (int)(key >> 20);
        unsigned sub = (key >> 8) & 0xFFFu;
        if (top == bn0) atomicAdd(&h2[(((size_t)b * 4 + 0) << 12) + sub], 1u);
        if (top == bn1) atomicAdd(&h2[(((size_t)b * 4 + 1) << 12) + sub], 1u);
        if (top == bn2) atomicAdd(&h2[(((size_t)b * 4 + 2) << 12) + sub], 1u);
        if (top == bn3) atomicAdd(&h2[(((size_t)b * 4 + 3) << 12) + sub], 1u);
    }
    unsigned nt = WS_TCNT(ws)[segid];
    const float* tupD = WS_TUPD(ws) + (size_t)segid * TSEGCAP;
    const float* tupG = WS_TUPG(ws) + (size_t)segid * TSEGCAP;
    const float* tupP = WS_TUPP(ws) + (size_t)segid * TSEGCAP;
    float* bufd = WS_BUFD(ws) + (size_t)b * CAP;
    float* bufa = WS_BUFA(ws) + (size_t)b * CAP;
    float* bufg = WS_BUFG(ws) + (size_t)b * CAP;
    for (unsigned i = tid; i < nt; i += 256) {
        float dg = tupG[i];
        float adg = fabsf(dg);
        if (adg < thub) {
            float d = s * tupD[i];
            unsigned pos = atomicAdd(&WS_CNT(ws)[b * 64], 1u);
            if (pos < CAP) {
                bufd[pos] = fabsf(d - dg);
                bufa[pos] = fabsf(d - tupP[i]);
                bufg[pos] = adg;
            }
        }
    }
}

// K6: per (batch, which): exact rr from H2, exact-th filter, trimmed-Huber via
// 3-level radix select. Last block (completion counter) writes the 4 scalars.
// grid (2, 16), block 256. (unchanged except faster locate_ranks)
__global__ __launch_bounds__(256) void k6_huber(float* __restrict__ out, unsigned char* ws) {
    __shared__ float v[CAP];
    __shared__ unsigned hist[4096];
    __shared__ unsigned part[256];
    __shared__ int ssub[4];
    __shared__ unsigned wtot[4];
    __shared__ unsigned sSel;
    __shared__ unsigned sRank;
    __shared__ float redf[4];
    __shared__ unsigned redc[4];
    __shared__ unsigned lk;
    int which = blockIdx.x, b = blockIdx.y, tid = threadIdx.x;
    int lane = tid & 63, wid = tid >> 6;
    const float* bufN = (which ? WS_BUFA(ws) : WS_BUFD(ws)) + (size_t)b * CAP;
    const float* bufG = WS_BUFG(ws) + (size_t)b * CAP;
    float* lout = which ? WS_LA(ws) : WS_LD(ws);

    // ---- exact quantile -> rr/th/sc (both which-blocks compute identically)
    int nmask = WS_NN(ws)[b];
    if (nmask > 0) {
        for (int q = 0; q < 4; q++) {
            int rq[1] = {(int)WS_RK(ws)[b * 4 + q]};
            unsigned dummyOff[1];
            locate_ranks(WS_H2(ws) + (((size_t)b * 4 + q) << 12), part, rq, 1, ssub + q, dummyOff);
        }
    }
    __syncthreads();
    float rr, th, sc;
    {
        float vals[4] = {0.f, 0.f, 0.f, 0.f};
        if (nmask > 0) {
            for (int q = 0; q < 4; q++) {
                unsigned key = (((unsigned)WS_BIN(ws)[b * 4 + q]) << 20) |
                               (((unsigned)ssub[q]) << 8) | 0x80u;   // mid of 256-ulp slot
                vals[q] = keyf(key);
            }
        }
        float f05 = WS_FR(ws)[b * 2 + 0], f95 = WS_FR(ws)[b * 2 + 1];
        float qlo = vals[0] + (vals[1] - vals[0]) * f05;
        float qhi = vals[2] + (vals[3] - vals[2]) * f95;
        bool valid = (nmask > 0) && isfinite(qlo) && isfinite(qhi) && (qhi - qlo > 0.0f) &&
                     (fabsf(qlo) < BIGF) && (fabsf(qhi) < BIGF);
        rr = valid ? fmaxf(qhi - qlo, 1e-6f) : 1.0f;
        th = 0.01f * rr;           // DIFF_RATIO
        sc = fmaxf(rr, 1e-6f);
        if (which == 0 && tid == 0) WS_RR(ws)[b] = rr;   // for final rr.mean()
    }

    // ---- exact-th filter of the conservative candidate set
    unsigned nraw = WS_CNT(ws)[b * 64];
    int ncons = (int)(nraw < (unsigned)CAP ? nraw : (unsigned)CAP);
    if (tid == 0) lk = 0;
    __syncthreads();
    for (int i = tid; i < ncons; i += 256) {
        float g = bufG[i];
        if (g < th) {
            unsigned p = atomicAdd(&lk, 1u);
            v[p] = bufN[i];
        }
    }
    __syncthreads();
    int n = (int)lk;
    int k = (int)floorf(0.6f * (float)n);   // (1-TRIM) in f32 — matches JAX promotion
    bool havek = (k > 0);

    if (havek) {
        unsigned selHi = 0;
        int rank = k - 1;
        for (int level = 0; level < 3; level++) {
            for (int i = tid; i < 4096; i += 256) hist[i] = 0;
            __syncthreads();
            for (int i = tid; i < n; i += 256) {
                unsigned key = __float_as_uint(v[i]);   // nonnegative -> order-monotone bits
                if (level == 0) {
                    atomicAdd(&hist[key >> 20], 1u);
                } else if (level == 1) {
                    if ((key >> 20) == selHi) atomicAdd(&hist[(key >> 8) & 0xFFFu], 1u);
                } else {
                    if ((key >> 8) == selHi) atomicAdd(&hist[key & 0xFFu], 1u);
                }
            }
            __syncthreads();
            int base = tid * 16;
            unsigned hloc[16];
            unsigned csum = 0;
#pragma unroll
            for (int j = 0; j < 16; j++) { hloc[j] = hist[base + j]; csum += hloc[j]; }
            unsigned incl = csum;
            for (int d = 1; d < 64; d <<= 1) {
                unsigned tshf = __shfl_up(incl, d);
                if (lane >= d) incl += tshf;
            }
            if (lane == 63) wtot[wid] = incl;
            __syncthreads();
            unsigned wadd = 0;
            for (int w = 0; w < wid; w++) wadd += wtot[w];
            incl += wadd;
            unsigned excl = incl - csum;
            if (rank >= (int)excl && rank < (int)incl) {
                unsigned cum = excl;
#pragma unroll
                for (int j = 0; j < 16; j++) {
                    unsigned h = hloc[j];
                    if ((unsigned)rank < cum + h) { sSel = (unsigned)(base + j); sRank = (unsigned)rank - cum; break; }
                    cum += h;
                }
            }
            __syncthreads();
            unsigned bin = sSel;
            rank = (int)sRank;
            if (level == 0) selHi = bin;
            else if (level == 1) selHi = (selHi << 12) | bin;
            else selHi = (selHi << 8) | bin;
        }
        unsigned Tkey = selHi;                  // exact bit pattern of k-th smallest numerator
        float T = __uint_as_float(Tkey);
        float sum = 0.0f;
        unsigned cnt = 0;
        for (int i = tid; i < n; i += 256) {
            float num = v[i];
            if (__float_as_uint(num) < Tkey) {
                float x = num / sc;
                sum += (x <= DELTAF) ? (0.5f * x * x / DELTAF) : (x - 0.5f * DELTAF);
                cnt++;
            }
        }
        for (int off = 32; off > 0; off >>= 1) {
            sum += __shfl_down(sum, off);
            cnt += __shfl_down(cnt, off);
        }
        if (lane == 0) { redf[wid] = sum; redc[wid] = cnt; }
        __syncthreads();
        if (tid == 0) {
            float tot = redf[0] + redf[1] + redf[2] + redf[3];
            unsigned c = redc[0] + redc[1] + redc[2] + redc[3];
            float xT = T / sc;
            float hubT = (xT <= DELTAF) ? (0.5f * xT * xT / DELTAF) : (xT - 0.5f * DELTAF);
            tot += (float)(k - (int)c) * hubT;
            lout[b] = tot / (float)k;
        }
    } else {
        if (tid == 0) lout[b] = 0.0f;
    }

    // ---- completion-counter finalize
    if (tid == 0) {
        __threadfence();
        unsigned done = atomicAdd(WS_DONE(ws), 1u);
        if (done == 2u * NB - 1u) {
            __threadfence();
            float ld = 0.f, la = 0.f, rm = 0.f;
            for (int bb = 0; bb < NB; bb++) {
                ld += WS_LD(ws)[bb];
                la += WS_LA(ws)[bb];
                rm += WS_RR(ws)[bb];
            }
            ld *= (1.0f / 16.0f);
            la *= (1.0f / 16.0f);
            rm *= (1.0f / 16.0f);
            out[0] = ld + 0.2f * la;   // LAMBDA_ACCEL
            out[1] = ld;
            out[2] = la;
            out[3] = rm;
        }
    }
}

extern "C" void kernel_launch(void* const* d_in, const int* in_sizes, int n_in,
                              void* d_out, int out_size, void* d_ws, size_t ws_size,
                              hipStream_t stream) {
    (void)in_sizes; (void)n_in; (void)out_size; (void)ws_size;
    const float* pred = (const float*)d_in[0];
    const float* gt   = (const float*)d_in[1];
    const float* mask = (const float*)d_in[2];
    const float* prev = (const float*)d_in[3];
    float* out = (float*)d_out;
    unsigned char* ws = (unsigned char*)d_ws;

    hipMemsetAsync(ws, 0, ZERO_BYTES, stream);
    k1_fused<<<dim3(NSEG, 16), 512, 0, stream>>>(pred, gt, mask, prev, out, ws);
    k2_rank_scale<<<dim3(60, 16), 256, 0, stream>>>(out, ws);
    k3_h2_filter<<<dim3(NSEG, 16), 256, 0, stream>>>(ws);
    k6_huber<<<dim3(2, 16), 256, 0, stream>>>(out, ws);
}

// Round 3
// 207.741 us; speedup vs baseline: 1.0286x; 1.0286x over previous
//
#include <hip/hip_runtime.h>
#include <math.h>

// Problem constants (B=16, T=2, H=384, W=640)
#define NB   16
#define HW_  245760          // H*W
#define THW_ 491520          // 2*H*W
#define CAP  2048            // per-batch final candidate capacity (~1440-1650 used)
#define BIGF 1e30f
#define DELTAF 0.03f
#define H1SLICES 8           // global L1-histogram slices (contention relief)
#define NSEG 60              // K1/K3 blocks per batch (4096 px each)
#define TSEGCAP 4096u        // tuples per segment (worst case: all px m12)
#define WCAP 512u            // per-wave sub-segment capacity (2 rounds * 4 px * 64 lanes)

// ---- workspace layout (bytes) ----
#define SUMS_OFF   0u                                   // double[16*5]
#define HIST1_OFF  1024u                                // uint[16*8*4096] sliced
#define HIST2_OFF  (HIST1_OFF + NB*H1SLICES*4096u*4u)   // uint[16*4*4096]
#define CNT_OFF    (HIST2_OFF + NB*4u*4096u*4u)         // uint[16*64] (256B padded per batch)
#define DONE_OFF   (CNT_OFF + NB*256u)                  // uint[1] k6 completion counter
#define ZERO_BYTES (DONE_OFF + 64u)
#define PAR_OFF    ((ZERO_BYTES + 255u) & ~255u)
#define S_OFF      (PAR_OFF + 0u)      // float[16]
#define T_OFF      (PAR_OFF + 64u)     // float[16]
#define RR_OFF     (PAR_OFF + 128u)    // float[16]
#define NN_OFF     (PAR_OFF + 320u)    // int[16]
#define BIN_OFF    (PAR_OFF + 384u)    // int[16*4]
#define RK_OFF     (PAR_OFF + 640u)    // uint[16*4]
#define FR_OFF     (PAR_OFF + 896u)    // float[16*2]
#define LD_OFF     (PAR_OFF + 1024u)   // float[16]
#define LA_OFF     (PAR_OFF + 1088u)   // float[16]
#define THUB_OFF   (PAR_OFF + 1152u)   // float[16] conservative th upper bound
#define BUFD_OFF   (PAR_OFF + 2048u)        // float[16*CAP] |dpred-dgt|
#define BUFA_OFF   (BUFD_OFF + NB*CAP*4u)   // float[16*CAP] |dpred-prev|
#define BUFG_OFF   (BUFA_OFF + NB*CAP*4u)   // float[16*CAP] |dgt|
#define TCNT_OFF   (BUFG_OFF + NB*CAP*4u)   // uint[16*60*8] per-(block,wave) tuple counts
#define TUP_OFF    ((TCNT_OFF + NB*NSEG*8u*4u + 255u) & ~255u)  // float4[16*60*4096] ≈ 61.4 MB

#define WS_SUMS(ws) ((double*)((ws) + SUMS_OFF))
#define WS_H1(ws)   ((unsigned*)((ws) + HIST1_OFF))
#define WS_H2(ws)   ((unsigned*)((ws) + HIST2_OFF))
#define WS_CNT(ws)  ((unsigned*)((ws) + CNT_OFF))      // index b*64
#define WS_DONE(ws) ((unsigned*)((ws) + DONE_OFF))
#define WS_S(ws)    ((float*)((ws) + S_OFF))
#define WS_T(ws)    ((float*)((ws) + T_OFF))
#define WS_RR(ws)   ((float*)((ws) + RR_OFF))
#define WS_NN(ws)   ((int*)((ws) + NN_OFF))
#define WS_BIN(ws)  ((int*)((ws) + BIN_OFF))
#define WS_RK(ws)   ((unsigned*)((ws) + RK_OFF))
#define WS_FR(ws)   ((float*)((ws) + FR_OFF))
#define WS_LD(ws)   ((float*)((ws) + LD_OFF))
#define WS_LA(ws)   ((float*)((ws) + LA_OFF))
#define WS_THUB(ws) ((float*)((ws) + THUB_OFF))
#define WS_BUFD(ws) ((float*)((ws) + BUFD_OFF))
#define WS_BUFA(ws) ((float*)((ws) + BUFA_OFF))
#define WS_BUFG(ws) ((float*)((ws) + BUFG_OFF))
#define WS_TCNT(ws) ((unsigned*)((ws) + TCNT_OFF))
#define WS_TUP(ws)  ((float4*)((ws) + TUP_OFF))

// order-preserving float<->uint key
__device__ __forceinline__ unsigned fkey(float x) {
    unsigned u = __float_as_uint(x);
    return (u & 0x80000000u) ? ~u : (u | 0x80000000u);
}
__device__ __forceinline__ float keyf(unsigned k) {
    unsigned u = (k & 0x80000000u) ? (k & 0x7fffffffu) : ~k;
    return __uint_as_float(u);
}

// Block-cooperative rank locate in a 4096-bin histogram (256 threads).
// Wave-level __shfl_up scan + 4 wave totals (2 barriers).
__device__ void locate_ranks(const unsigned* __restrict__ hist, unsigned* part,
                             const int* ranks, int nr, int* outBin, unsigned* outOff) {
    int tid = threadIdx.x;
    int lane = tid & 63, wid = tid >> 6;
    int base = tid * 16;
    unsigned hloc[16];
    unsigned csum = 0;
#pragma unroll
    for (int j = 0; j < 16; j++) { hloc[j] = hist[base + j]; csum += hloc[j]; }
    unsigned incl = csum;
#pragma unroll
    for (int d = 1; d < 64; d <<= 1) {
        unsigned t = __shfl_up(incl, d);
        if (lane >= d) incl += t;
    }
    if (lane == 63) part[wid] = incl;
    __syncthreads();
    unsigned wadd = 0;
    for (int w = 0; w < wid; w++) wadd += part[w];
    incl += wadd;
    unsigned excl = incl - csum;
    for (int q = 0; q < nr; q++) {
        int r = ranks[q];
        if (r >= (int)excl && r < (int)incl) {
            unsigned cum = excl;
#pragma unroll
            for (int j = 0; j < 16; j++) {
                unsigned h = hloc[j];
                if ((unsigned)r < cum + h) { outBin[q] = base + j; outOff[q] = (unsigned)r - cum; break; }
                cum += h;
            }
        }
    }
    __syncthreads();
}

// K1 (lean): single pass. Per-batch regression sums (f64), L1 histogram of
// masked gt, raw dp=p1-p0 -> out (t cancels; scaled by s in k3), and
// ATOMIC-FREE per-wave ballot-compacted spill of m12 tuples (dp,dg,prev,0)
// into per-(block,wave) worst-case-sized sub-segments. No key spill (k3
// re-reads gt/mask from L3 instead). grid (60,16), block 512: 4096 px/block;
// 7680 waves = 7.5/SIMD for latency hiding (r1 was grid-limited to 3.75).
__global__ __launch_bounds__(512, 8) void k1_fused(const float* __restrict__ pred,
                                                   const float* __restrict__ gt,
                                                   const float* __restrict__ mask,
                                                   const float* __restrict__ prev,
                                                   float* __restrict__ out,
                                                   unsigned char* __restrict__ ws) {
    __shared__ unsigned hist[8192];
    __shared__ double red[8][5];
    int tid = threadIdx.x, b = blockIdx.y, x = blockIdx.x;
    int lane = tid & 63, wid = tid >> 6;
    unsigned half = (tid >> 5) & 1u;
    for (int i = tid; i < 8192; i += 512) hist[i] = 0;
    __syncthreads();

    size_t hw0 = (size_t)x * 4096;
    const float* p0p = pred + (size_t)b * THW_ + hw0;
    const float* g0p = gt   + (size_t)b * THW_ + hw0;
    const float* m0p = mask + (size_t)b * THW_ + hw0;
    const float* pvp = prev + (size_t)b * HW_  + hw0;
    float* op = out + 4 + (size_t)b * HW_ + hw0;
    int segid = b * NSEG + x;
    float4* tw = WS_TUP(ws) + (size_t)segid * TSEGCAP + (size_t)wid * WCAP;
    unsigned long long premask = (1ull << lane) - 1ull;
    unsigned wofs = 0;   // wave-uniform running tuple count

    double a00 = 0, a01 = 0, a11 = 0, sb0 = 0, sb1 = 0;
#pragma unroll
    for (int r = 0; r < 2; r++) {
        size_t o = (size_t)r * 2048 + (size_t)tid * 4;
        float4 P0 = *(const float4*)(p0p + o);
        float4 P1 = *(const float4*)(p0p + HW_ + o);
        float4 G0 = *(const float4*)(g0p + o);
        float4 G1 = *(const float4*)(g0p + HW_ + o);
        float4 M0 = *(const float4*)(m0p + o);
        float4 M1 = *(const float4*)(m0p + HW_ + o);
        float4 PV = *(const float4*)(pvp + o);
        float dp0, dp1, dp2, dp3;
        // Per component: sums+hist for each masked frame, ballot-compacted
        // m12 tuple append (no atomics, no runtime-indexed register arrays).
#define DOC(P0c, P1c, G0c, G1c, M0c, M1c, PVc, DPc)                          \
        {                                                                    \
            bool mm0 = (M0c) > 0.5f, mm1 = (M1c) > 0.5f;                     \
            DPc = (P1c) - (P0c);                                             \
            if (mm0) {                                                       \
                a00 += (double)((P0c) * (P0c)); a01 += (double)(P0c);        \
                a11 += 1.0;                                                  \
                sb0 += (double)((P0c) * (G0c)); sb1 += (double)(G0c);        \
                atomicAdd(&hist[((fkey(G0c) >> 20) << 1) | half], 1u);       \
            }                                                                \
            if (mm1) {                                                       \
                a00 += (double)((P1c) * (P1c)); a01 += (double)(P1c);        \
                a11 += 1.0;                                                  \
                sb0 += (double)((P1c) * (G1c)); sb1 += (double)(G1c);        \
                atomicAdd(&hist[((fkey(G1c) >> 20) << 1) | half], 1u);       \
            }                                                                \
            bool m12 = mm0 && mm1;                                           \
            unsigned long long bal = __ballot(m12);                          \
            if (bal) {                                                       \
                unsigned pre = (unsigned)__popcll(bal & premask);            \
                if (m12) tw[wofs + pre] =                                    \
                    make_float4(DPc, (G1c) - (G0c), (PVc), 0.0f);            \
                wofs += (unsigned)__popcll(bal);                             \
            }                                                                \
        }
        DOC(P0.x, P1.x, G0.x, G1.x, M0.x, M1.x, PV.x, dp0)
        DOC(P0.y, P1.y, G0.y, G1.y, M0.y, M1.y, PV.y, dp1)
        DOC(P0.z, P1.z, G0.z, G1.z, M0.z, M1.z, PV.z, dp2)
        DOC(P0.w, P1.w, G0.w, G1.w, M0.w, M1.w, PV.w, dp3)
#undef DOC
        *(float4*)(op + o) = make_float4(dp0, dp1, dp2, dp3);
    }
    if (lane == 0) WS_TCNT(ws)[segid * 8 + wid] = wofs;
    __syncthreads();
    // flush nonzero bins to this block's slice, rotated start spreads lines
    unsigned* gh = WS_H1(ws) + ((size_t)b * H1SLICES + (unsigned)(x & (H1SLICES - 1))) * 4096u;
    unsigned rot = ((unsigned)x * 331u) & 4095u;
    for (int i = tid; i < 4096; i += 512) {
        int bin = (int)(((unsigned)i + rot) & 4095u);
        unsigned v = hist[bin * 2] + hist[bin * 2 + 1];
        if (v) atomicAdd(&gh[bin], v);
    }
    double acc[5] = {a00, a01, a11, sb0, sb1};
#pragma unroll
    for (int j = 0; j < 5; j++) {
        double v = acc[j];
        for (int o2 = 32; o2 > 0; o2 >>= 1) v += __shfl_down(v, o2);
        if (lane == 0) red[wid][j] = v;
    }
    __syncthreads();
    if (tid == 0) {
        double* gs = WS_SUMS(ws) + b * 5;
#pragma unroll
        for (int j = 0; j < 5; j++) {
            double tot = 0.0;
#pragma unroll
            for (int w = 0; w < 8; w++) tot += red[w][j];
            atomicAdd(&gs[j], tot);
        }
    }
}

// K2 (rank-only, 16 blocks x 256): s,t,NN; sum H1 slices; quantile ranks;
// L1 bins; th_ub. The out-scaling moved to k3.
__global__ __launch_bounds__(256) void k2_rank(unsigned char* __restrict__ ws) {
    __shared__ unsigned hsum[4096];
    __shared__ unsigned part[256];
    int b = blockIdx.x, tid = threadIdx.x;
    const double* gs = WS_SUMS(ws) + b * 5;
    double a00 = gs[0], a01 = gs[1], a11 = gs[2], b0 = gs[3], b1 = gs[4];
    double det = a00 * a11 - a01 * a01;
    int n = (int)(a11 + 0.5);
    if (tid == 0) {
        double x0 = 0.0, x1 = 0.0;
        if (det != 0.0) {
            x0 = (a11 * b0 - a01 * b1) / (det + 1e-6);
            x1 = (-a01 * b0 + a00 * b1) / (det + 1e-6);
        }
        WS_S(ws)[b] = (float)x0;
        WS_T(ws)[b] = (float)x1;
        WS_NN(ws)[b] = n;
    }
    // reduce slices: thread t owns bins [t*16, t*16+16)
    {
        const unsigned* h1 = WS_H1(ws) + (size_t)b * H1SLICES * 4096u;
        int base = tid * 16;
        unsigned acc[16];
#pragma unroll
        for (int j = 0; j < 16; j++) acc[j] = 0;
        for (int s = 0; s < H1SLICES; s++) {
            const unsigned* hs = h1 + (size_t)s * 4096u + base;
#pragma unroll
            for (int j = 0; j < 16; j++) acc[j] += hs[j];
        }
#pragma unroll
        for (int j = 0; j < 16; j++) hsum[base + j] = acc[j];
    }
    __syncthreads();
    float nm1 = (float)((n - 1 > 0) ? (n - 1) : 0);
    float p05 = 0.05f * nm1, p95 = 0.95f * nm1;   // f32 to match JAX weak-type promotion
    int ranks[4] = {(int)floorf(p05), (int)ceilf(p05), (int)floorf(p95), (int)ceilf(p95)};
    float f05 = p05 - floorf(p05), f95 = p95 - floorf(p95);
    if (tid == 0) {
        WS_FR(ws)[b * 2 + 0] = f05;
        WS_FR(ws)[b * 2 + 1] = f95;
    }
    if (n > 0) {
        locate_ranks(hsum, part, ranks, 4, WS_BIN(ws) + b * 4, WS_RK(ws) + b * 4);
        if (tid == 0) {
            const int* bp = WS_BIN(ws) + b * 4;
            float lb0 = keyf(((unsigned)bp[0]) << 20), ub0 = keyf((((unsigned)bp[0]) << 20) | 0xFFFFFu);
            float lb1 = keyf(((unsigned)bp[1]) << 20), ub1 = keyf((((unsigned)bp[1]) << 20) | 0xFFFFFu);
            float lb2 = keyf(((unsigned)bp[2]) << 20), ub2 = keyf((((unsigned)bp[2]) << 20) | 0xFFFFFu);
            float lb3 = keyf(((unsigned)bp[3]) << 20), ub3 = keyf((((unsigned)bp[3]) << 20) | 0xFFFFFu);
            float qlo_lb = (1.0f - f05) * lb0 + f05 * lb1;
            float qlo_ub = (1.0f - f05) * ub0 + f05 * ub1;
            float qhi_lb = (1.0f - f95) * lb2 + f95 * lb3;
            float qhi_ub = (1.0f - f95) * ub2 + f95 * ub3;
            float rr_ub = fmaxf(qhi_ub - qlo_lb, 1e-6f);
            if (qhi_lb - qlo_ub <= 0.0f) rr_ub = fmaxf(rr_ub, 1.0f);
            WS_THUB(ws)[b] = 0.01f * rr_ub * 1.0001f;   // tiny safety margin
        }
    } else if (tid == 0) {
        WS_THUB(ws)[b] = 0.0f;   // no masked pixels -> nothing static
        int* bp = WS_BIN(ws) + b * 4;
        bp[0] = bp[1] = bp[2] = bp[3] = -1;
    }
}

// K3: out scaling (in place, s from k2 — bit-identical to r1's k2 path),
// H2 population from L3-warm gt/mask re-read, and exact-conservative thub
// filter of the spilled tuples into the CAP buffers. grid (60,16), block 512.
__global__ __launch_bounds__(512) void k3_scale_h2_filter(const float* __restrict__ gt,
                                                          const float* __restrict__ mask,
                                                          float* __restrict__ out,
                                                          unsigned char* __restrict__ ws) {
    int tid = threadIdx.x, b = blockIdx.y, x = blockIdx.x;
    float s = WS_S(ws)[b], thub = WS_THUB(ws)[b];
    const int* bp = WS_BIN(ws) + b * 4;
    int bn0 = bp[0], bn1 = bp[1], bn2 = bp[2], bn3 = bp[3];
    unsigned* h2 = WS_H2(ws);
    size_t hw0 = (size_t)x * 4096;
    const float* g0p = gt + (size_t)b * THW_ + hw0;
    const float* m0p = mask + (size_t)b * THW_ + hw0;
    float* op = out + 4 + (size_t)b * HW_ + hw0;
#pragma unroll
    for (int r = 0; r < 2; r++) {
        size_t o = (size_t)r * 2048 + (size_t)tid * 4;
        float4 G0 = *(const float4*)(g0p + o);
        float4 G1 = *(const float4*)(g0p + HW_ + o);
        float4 M0 = *(const float4*)(m0p + o);
        float4 M1 = *(const float4*)(m0p + HW_ + o);
        float4 D = *(const float4*)(op + o);
        D.x *= s; D.y *= s; D.z *= s; D.w *= s;
        *(float4*)(op + o) = D;
#define DOH(Gc, Mc)                                                              \
        if ((Mc) > 0.5f) {                                                       \
            unsigned key = fkey(Gc);                                             \
            int top = (int)(key >> 20);                                          \
            unsigned sub = (key >> 8) & 0xFFFu;                                  \
            if (top == bn0) atomicAdd(&h2[(((size_t)b * 4 + 0) << 12) + sub], 1u); \
            if (top == bn1) atomicAdd(&h2[(((size_t)b * 4 + 1) << 12) + sub], 1u); \
            if (top == bn2) atomicAdd(&h2[(((size_t)b * 4 + 2) << 12) + sub], 1u); \
            if (top == bn3) atomicAdd(&h2[(((size_t)b * 4 + 3) << 12) + sub], 1u); \
        }
        DOH(G0.x, M0.x)
        DOH(G0.y, M0.y)
        DOH(G0.z, M0.z)
        DOH(G0.w, M0.w)
        DOH(G1.x, M1.x)
        DOH(G1.y, M1.y)
        DOH(G1.z, M1.z)
        DOH(G1.w, M1.w)
#undef DOH
    }
    // tuple filter: 8 per-wave sub-segments of this block's k1 segment
    int segid = b * NSEG + x;
    const float4* tseg = WS_TUP(ws) + (size_t)segid * TSEGCAP;
    const unsigned* tc = WS_TCNT(ws) + segid * 8;
    float* bufd = WS_BUFD(ws) + (size_t)b * CAP;
    float* bufa = WS_BUFA(ws) + (size_t)b * CAP;
    float* bufg = WS_BUFG(ws) + (size_t)b * CAP;
    for (int w = 0; w < 8; w++) {
        unsigned cnt = tc[w];
        const float4* sub = tseg + (size_t)w * WCAP;
        for (unsigned i = tid; i < cnt; i += 512) {
            float4 t = sub[i];
            float adg = fabsf(t.y);
            if (adg < thub) {
                float d = s * t.x;
                unsigned pos = atomicAdd(&WS_CNT(ws)[b * 64], 1u);
                if (pos < CAP) {
                    bufd[pos] = fabsf(d - t.y);
                    bufa[pos] = fabsf(d - t.z);
                    bufg[pos] = adg;
                }
            }
        }
    }
}

// K6: per (batch, which): exact rr from H2, exact-th filter, trimmed-Huber via
// 3-level radix select. Last block (completion counter) writes the 4 scalars.
// grid (2, 16), block 256.
__global__ __launch_bounds__(256) void k6_huber(float* __restrict__ out, unsigned char* ws) {
    __shared__ float v[CAP];
    __shared__ unsigned hist[4096];
    __shared__ unsigned part[256];
    __shared__ int ssub[4];
    __shared__ unsigned wtot[4];
    __shared__ unsigned sSel;
    __shared__ unsigned sRank;
    __shared__ float redf[4];
    __shared__ unsigned redc[4];
    __shared__ unsigned lk;
    int which = blockIdx.x, b = blockIdx.y, tid = threadIdx.x;
    int lane = tid & 63, wid = tid >> 6;
    const float* bufN = (which ? WS_BUFA(ws) : WS_BUFD(ws)) + (size_t)b * CAP;
    const float* bufG = WS_BUFG(ws) + (size_t)b * CAP;
    float* lout = which ? WS_LA(ws) : WS_LD(ws);

    // ---- exact quantile -> rr/th/sc (both which-blocks compute identically)
    int nmask = WS_NN(ws)[b];
    if (nmask > 0) {
        for (int q = 0; q < 4; q++) {
            int rq[1] = {(int)WS_RK(ws)[b * 4 + q]};
            unsigned dummyOff[1];
            locate_ranks(WS_H2(ws) + (((size_t)b * 4 + q) << 12), part, rq, 1, ssub + q, dummyOff);
        }
    }
    __syncthreads();
    float rr, th, sc;
    {
        float vals[4] = {0.f, 0.f, 0.f, 0.f};
        if (nmask > 0) {
            for (int q = 0; q < 4; q++) {
                unsigned key = (((unsigned)WS_BIN(ws)[b * 4 + q]) << 20) |
                               (((unsigned)ssub[q]) << 8) | 0x80u;   // mid of 256-ulp slot
                vals[q] = keyf(key);
            }
        }
        float f05 = WS_FR(ws)[b * 2 + 0], f95 = WS_FR(ws)[b * 2 + 1];
        float qlo = vals[0] + (vals[1] - vals[0]) * f05;
        float qhi = vals[2] + (vals[3] - vals[2]) * f95;
        bool valid = (nmask > 0) && isfinite(qlo) && isfinite(qhi) && (qhi - qlo > 0.0f) &&
                     (fabsf(qlo) < BIGF) && (fabsf(qhi) < BIGF);
        rr = valid ? fmaxf(qhi - qlo, 1e-6f) : 1.0f;
        th = 0.01f * rr;           // DIFF_RATIO
        sc = fmaxf(rr, 1e-6f);
        if (which == 0 && tid == 0) WS_RR(ws)[b] = rr;   // for final rr.mean()
    }

    // ---- exact-th filter of the conservative candidate set
    unsigned nraw = WS_CNT(ws)[b * 64];
    int ncons = (int)(nraw < (unsigned)CAP ? nraw : (unsigned)CAP);
    if (tid == 0) lk = 0;
    __syncthreads();
    for (int i = tid; i < ncons; i += 256) {
        float g = bufG[i];
        if (g < th) {
            unsigned p = atomicAdd(&lk, 1u);
            v[p] = bufN[i];
        }
    }
    __syncthreads();
    int n = (int)lk;
    int k = (int)floorf(0.6f * (float)n);   // (1-TRIM) in f32 — matches JAX promotion
    bool havek = (k > 0);

    if (havek) {
        unsigned selHi = 0;
        int rank = k - 1;
        for (int level = 0; level < 3; level++) {
            for (int i = tid; i < 4096; i += 256) hist[i] = 0;
            __syncthreads();
            for (int i = tid; i < n; i += 256) {
                unsigned key = __float_as_uint(v[i]);   // nonnegative -> order-monotone bits
                if (level == 0) {
                    atomicAdd(&hist[key >> 20], 1u);
                } else if (level == 1) {
                    if ((key >> 20) == selHi) atomicAdd(&hist[(key >> 8) & 0xFFFu], 1u);
                } else {
                    if ((key >> 8) == selHi) atomicAdd(&hist[key & 0xFFu], 1u);
                }
            }
            __syncthreads();
            int base = tid * 16;
            unsigned hloc[16];
            unsigned csum = 0;
#pragma unroll
            for (int j = 0; j < 16; j++) { hloc[j] = hist[base + j]; csum += hloc[j]; }
            unsigned incl = csum;
            for (int d = 1; d < 64; d <<= 1) {
                unsigned tshf = __shfl_up(incl, d);
                if (lane >= d) incl += tshf;
            }
            if (lane == 63) wtot[wid] = incl;
            __syncthreads();
            unsigned wadd = 0;
            for (int w = 0; w < wid; w++) wadd += wtot[w];
            incl += wadd;
            unsigned excl = incl - csum;
            if (rank >= (int)excl && rank < (int)incl) {
                unsigned cum = excl;
#pragma unroll
                for (int j = 0; j < 16; j++) {
                    unsigned h = hloc[j];
                    if ((unsigned)rank < cum + h) { sSel = (unsigned)(base + j); sRank = (unsigned)rank - cum; break; }
                    cum += h;
                }
            }
            __syncthreads();
            unsigned bin = sSel;
            rank = (int)sRank;
            if (level == 0) selHi = bin;
            else if (level == 1) selHi = (selHi << 12) | bin;
            else selHi = (selHi << 8) | bin;
        }
        unsigned Tkey = selHi;                  // exact bit pattern of k-th smallest numerator
        float T = __uint_as_float(Tkey);
        float sum = 0.0f;
        unsigned cnt = 0;
        for (int i = tid; i < n; i += 256) {
            float num = v[i];
            if (__float_as_uint(num) < Tkey) {
                float x = num / sc;
                sum += (x <= DELTAF) ? (0.5f * x * x / DELTAF) : (x - 0.5f * DELTAF);
                cnt++;
            }
        }
        for (int off = 32; off > 0; off >>= 1) {
            sum += __shfl_down(sum, off);
            cnt += __shfl_down(cnt, off);
        }
        if (lane == 0) { redf[wid] = sum; redc[wid] = cnt; }
        __syncthreads();
        if (tid == 0) {
            float tot = redf[0] + redf[1] + redf[2] + redf[3];
            unsigned c = redc[0] + redc[1] + redc[2] + redc[3];
            float xT = T / sc;
            float hubT = (xT <= DELTAF) ? (0.5f * xT * xT / DELTAF) : (xT - 0.5f * DELTAF);
            tot += (float)(k - (int)c) * hubT;
            lout[b] = tot / (float)k;
        }
    } else {
        if (tid == 0) lout[b] = 0.0f;
    }

    // ---- completion-counter finalize
    if (tid == 0) {
        __threadfence();
        unsigned done = atomicAdd(WS_DONE(ws), 1u);
        if (done == 2u * NB - 1u) {
            __threadfence();
            float ld = 0.f, la = 0.f, rm = 0.f;
            for (int bb = 0; bb < NB; bb++) {
                ld += WS_LD(ws)[bb];
                la += WS_LA(ws)[bb];
                rm += WS_RR(ws)[bb];
            }
            ld *= (1.0f / 16.0f);
            la *= (1.0f / 16.0f);
            rm *= (1.0f / 16.0f);
            out[0] = ld + 0.2f * la;   // LAMBDA_ACCEL
            out[1] = ld;
            out[2] = la;
            out[3] = rm;
        }
    }
}

extern "C" void kernel_launch(void* const* d_in, const int* in_sizes, int n_in,
                              void* d_out, int out_size, void* d_ws, size_t ws_size,
                              hipStream_t stream) {
    (void)in_sizes; (void)n_in; (void)out_size; (void)ws_size;
    const float* pred = (const float*)d_in[0];
    const float* gt   = (const float*)d_in[1];
    const float* mask = (const float*)d_in[2];
    const float* prev = (const float*)d_in[3];
    float* out = (float*)d_out;
    unsigned char* ws = (unsigned char*)d_ws;

    hipMemsetAsync(ws, 0, ZERO_BYTES, stream);
    k1_fused<<<dim3(NSEG, 16), 512, 0, stream>>>(pred, gt, mask, prev, out, ws);
    k2_rank<<<16, 256, 0, stream>>>(ws);
    k3_scale_h2_filter<<<dim3(NSEG, 16), 512, 0, stream>>>(gt, mask, out, ws);
    k6_huber<<<dim3(2, 16), 256, 0, stream>>>(out, ws);
}